// Round 6
// baseline (760.391 us; speedup 1.0000x reference)
//
#include <hip/hip_runtime.h>
#include <math.h>

#define BATCH 128
#define T 250
#define D_IN 700
#define H 256
#define D_OUT 20

typedef float v2f __attribute__((ext_vector_type(2)));
typedef __attribute__((ext_vector_type(8))) short bf16x8;
typedef __attribute__((ext_vector_type(8))) unsigned short ushort8;
typedef __attribute__((ext_vector_type(4))) float f32x4;
typedef __attribute__((ext_vector_type(4))) unsigned u32x4;

static __device__ __forceinline__ unsigned short f2b(float f) {
    unsigned u = __float_as_uint(f);
    u += 0x7FFFu + ((u >> 16) & 1u);
    return (unsigned short)(u >> 16);
}

// Raw barrier: LDS ordering only (lgkmcnt). No vmcnt drain so global loads
// (u_nxt prefetch, asm gather pipeline) stay in flight across it.
static __device__ __forceinline__ void bar() {
    asm volatile("s_waitcnt lgkmcnt(0)" ::: "memory");
    __builtin_amdgcn_s_barrier();
    asm volatile("" ::: "memory");
}

// ---------------------------------------------------------------------------
// Workspace layout (unchanged from R5):
//   U     [32001][256] f32    (pad row: u-prefetch overrun at t=249)
//   C1    [257][512] bf16     row k, lane l: {W12T[k][4l..4l+3], W11T[k][4l..4l+3]}
//   C2    [257][512] bf16     row k, lane l: {W22T[k][4l..4l+3], Wo[l&31][k],0,0,0}
//   Wi1p  [256][704] bf16     cols 700..703 zero (MFMA K-pad)
//   row 256 of C1/C2 is all-zero (spike-list padding target)
//
// R6: SAME structure as R5; the gather loads become inline-asm
// global_load_dwordx4 with counted s_waitcnt vmcnt(N) + sched_barrier(0).
// Asm outputs cannot be collapsed by the register allocator -> depth 32/wave
// is structural (R2/R3/R5 all collapsed to ~8 rows at HIP source level).
// ---------------------------------------------------------------------------
#define N_C  (257 * 512)
#define N_WP (256 * 704)

__global__ void prep_k(const float* __restrict__ Wi1, const float* __restrict__ W11,
                       const float* __restrict__ W12, const float* __restrict__ W22,
                       const float* __restrict__ Wo,
                       unsigned short* __restrict__ Wi1p, unsigned short* __restrict__ C1,
                       unsigned short* __restrict__ C2) {
    int idx = blockIdx.x * 256 + threadIdx.x;
    if (idx < N_C) {
        int k = idx >> 9, q = idx & 511;
        int l = q >> 3, jj = q & 7;
        float v = 0.f;
        if (k < H) {
            int h = 4 * l + (jj & 3);
            v = (jj < 4) ? W12[h * H + k] : W11[h * H + k];
        }
        C1[idx] = f2b(v);
        return;
    }
    idx -= N_C;
    if (idx < N_C) {
        int k = idx >> 9, q = idx & 511;
        int l = q >> 3, jj = q & 7;
        float v = 0.f;
        if (k < H) {
            if (jj < 4) v = W22[(4 * l + jj) * H + k];
            else if (jj == 4 && (l & 31) < D_OUT) v = Wo[(l & 31) * H + k];
        }
        C2[idx] = f2b(v);
        return;
    }
    idx -= N_C;
    if (idx < N_WP) {
        int h = idx / 704, k = idx - h * 704;
        Wi1p[idx] = (k < D_IN) ? f2b(Wi1[h * D_IN + k]) : (unsigned short)0;
    }
}

// ---------------------------------------------------------------------------
// U = x @ Wi1^T + bi1 via MFMA 16x16x32 bf16 — UNCHANGED (proven).
// ---------------------------------------------------------------------------
__global__ __launch_bounds__(256) void gemm_u_k(const float* __restrict__ x,
                                                const unsigned short* __restrict__ Wi1p,
                                                const float* __restrict__ bi1,
                                                float* __restrict__ U) {
    const int lane = threadIdx.x & 63;
    const int wv = threadIdx.x >> 6;
    const int quad = lane >> 4;
    const int nl = lane & 15;
    const int mbase = blockIdx.x * 64 + wv * 16;
    const int m = mbase + nl;

    f32x4 acc[16];
#pragma unroll
    for (int i = 0; i < 16; ++i) acc[i] = (f32x4)(0.f);

    float bias[16];
#pragma unroll
    for (int nt = 0; nt < 16; ++nt) bias[nt] = bi1[nt * 16 + nl];

    const float* xrow = x + (size_t)m * D_IN;
    const unsigned short* brow = Wi1p + nl * 704 + quad * 8;

    for (int k0 = 0; k0 < 704; k0 += 32) {
        int ka = k0 + quad * 8;
        int ka2 = (ka + 4 <= 696) ? ka + 4 : 696;
        float4 q0 = *(const float4*)(xrow + ka);
        float4 q1 = *(const float4*)(xrow + ka2);
        bf16x8 af;
        af[0] = (short)f2b(q0.x); af[1] = (short)f2b(q0.y);
        af[2] = (short)f2b(q0.z); af[3] = (short)f2b(q0.w);
        af[4] = (short)f2b(q1.x); af[5] = (short)f2b(q1.y);
        af[6] = (short)f2b(q1.z); af[7] = (short)f2b(q1.w);

        const unsigned short* bp = brow + k0;
        bf16x8 bf[16];
#pragma unroll
        for (int nt = 0; nt < 16; ++nt)
            bf[nt] = *(const bf16x8*)(bp + nt * 16 * 704);
#pragma unroll
        for (int nt = 0; nt < 16; ++nt)
            acc[nt] = __builtin_amdgcn_mfma_f32_16x16x32_bf16(af, bf[nt], acc[nt], 0, 0, 0);
    }

#pragma unroll
    for (int nt = 0; nt < 16; ++nt) {
#pragma unroll
        for (int r = 0; r < 4; ++r) {
            U[(size_t)(mbase + quad * 4 + r) * H + nt * 16 + nl] = acc[nt][r] + bias[nt];
        }
    }
}

// ---------------------------------------------------------------------------
// Spike-list build by wave 0 (R7-proven): 4 ballots, compacted list + 64 pads
// pointing at the all-zero row 256.
// ---------------------------------------------------------------------------
__device__ __forceinline__ int build_list(unsigned int* list, int lane,
                                          float sx, float sy, float sz, float sw) {
    unsigned long long m0 = __ballot(sx > 0.f);
    unsigned long long m1 = __ballot(sy > 0.f);
    unsigned long long m2 = __ballot(sz > 0.f);
    unsigned long long m3 = __ballot(sw > 0.f);
    unsigned long long below = (1ull << lane) - 1ull;
    int c0 = __popcll(m0), c1 = __popcll(m1), c2 = __popcll(m2), c3 = __popcll(m3);
    int n = c0 + c1 + c2 + c3;
    if ((m0 >> lane) & 1) list[__popcll(m0 & below)] = lane * 4;
    if ((m1 >> lane) & 1) list[c0 + __popcll(m1 & below)] = lane * 4 + 1;
    if ((m2 >> lane) & 1) list[c0 + c1 + __popcll(m2 & below)] = lane * 4 + 2;
    if ((m3 >> lane) & 1) list[c0 + c1 + c2 + __popcll(m3 & below)] = lane * 4 + 3;
    list[n + lane] = 256;                   // 64 pad entries -> zero weight row
    __builtin_amdgcn_wave_barrier();
    return n;
}

// ---------------------------------------------------------------------------
// Asm-issued 16-row chunk: 16 global_load_dwordx4 whose destinations are asm
// outputs — the allocator must materialize all 64 VGPRs, the scheduler cannot
// sink them. Waits are explicit counted vmcnt (safe under compiler-interleaved
// loads: extra loads only make the wait more conservative).
// ---------------------------------------------------------------------------
static __device__ __forceinline__ void issue16(const unsigned* __restrict__ lst, int c,
                                               const unsigned short* __restrict__ Cb,
                                               unsigned soff, u32x4* buf) {
    uint4 A = *(const uint4*)(lst + c);
    uint4 Bv = *(const uint4*)(lst + c + 4);
    uint4 Dv = *(const uint4*)(lst + c + 8);
    uint4 Ev = *(const uint4*)(lst + c + 12);
    unsigned I[16] = {A.x, A.y, A.z, A.w, Bv.x, Bv.y, Bv.z, Bv.w,
                      Dv.x, Dv.y, Dv.z, Dv.w, Ev.x, Ev.y, Ev.z, Ev.w};
#pragma unroll
    for (int j = 0; j < 16; ++j) {
        const unsigned short* p = Cb + ((unsigned)I[j] << 9) + soff;
        asm volatile("global_load_dwordx4 %0, %1, off"
                     : "=&v"(buf[j]) : "v"(p));
    }
}

static __device__ __forceinline__ void acc16(const u32x4* buf, v2f* a) {
#pragma unroll
    for (int j = 0; j < 16; ++j) {
        u32x4 d = buf[j];
#pragma unroll
        for (int q = 0; q < 4; ++q) {
            unsigned u = d[q];
            v2f t;
            t.x = __uint_as_float(u << 16);
            t.y = __uint_as_float(u & 0xffff0000u);
            a[q] += t;
        }
    }
}

#define WAIT_VM(N) do { \
    asm volatile("s_waitcnt vmcnt(" #N ")" ::: "memory"); \
    __builtin_amdgcn_sched_barrier(0); \
} while (0)

// Striped per-wave gather: wave w takes 16-row chunks {c0, c0+64, c0+128,
// c0+192}, depth-32 asm pipeline (2 chunks in flight).
static __device__ __forceinline__ void gatherP(const unsigned* __restrict__ lst, int nr16,
                                               int w, const unsigned short* __restrict__ Cb,
                                               unsigned soff, v2f* a) {
    a[0] = (v2f)(0.f); a[1] = (v2f)(0.f); a[2] = (v2f)(0.f); a[3] = (v2f)(0.f);
    u32x4 b0[16], b1[16];
    const int c0 = w * 16, c1 = c0 + 64, c2v = c0 + 128, c3 = c0 + 192;
    const bool h0 = c0 < nr16, h1 = c1 < nr16, h2 = c2v < nr16, h3 = c3 < nr16;
    if (h0) issue16(lst, c0, Cb, soff, b0);
    if (h1) issue16(lst, c1, Cb, soff, b1);
    if (h0) {
        if (h1) { WAIT_VM(16); } else { WAIT_VM(0); }
        acc16(b0, a);
    }
    if (h2) issue16(lst, c2v, Cb, soff, b0);
    if (h1) {
        if (h2) { WAIT_VM(16); } else { WAIT_VM(0); }
        acc16(b1, a);
    }
    if (h3) issue16(lst, c3, Cb, soff, b1);
    if (h2) {
        if (h3) { WAIT_VM(16); } else { WAIT_VM(0); }
        acc16(b0, a);
    }
    if (h3) {
        WAIT_VM(0);
        acc16(b1, a);
    }
}

// ---------------------------------------------------------------------------
// Recurrent: one BLOCK (4 waves, 256 threads) per batch element.
// Wave 0: full neuron state (4 neurons/lane quads), list build, reduce.
// Waves 0-3: striped asm-pipelined gathers + slot-major LDS partials.
// Wave 1: output (memo/softmax/acc) chain, off wave-0's critical path.
// ---------------------------------------------------------------------------
__global__ __launch_bounds__(256, 1) void recurrent_k(
    const float* __restrict__ U,
    const float* __restrict__ mem1_0, const float* __restrict__ mem2_0,
    const float* __restrict__ memo_0,
    const float* __restrict__ b11v, const float* __restrict__ b12v,
    const float* __restrict__ b22v, const float* __restrict__ bov,
    const float* __restrict__ tau_adp_h1, const float* __restrict__ tau_adp_h2,
    const float* __restrict__ tau_m_h1, const float* __restrict__ tau_m_h2,
    const float* __restrict__ tau_m_o,
    const unsigned short* __restrict__ C1, const unsigned short* __restrict__ C2,
    float* __restrict__ out)
{
    const int tid = threadIdx.x;
    const int lane = tid & 63;
    const int w = tid >> 6;
    const int bi = blockIdx.x;
    const unsigned laneOff = lane * 4;
    const unsigned soff = (unsigned)lane * 8;   // ushort offset into 512-elem row

    __shared__ __align__(16) unsigned list1[320], list2[320];
    __shared__ unsigned cnt1s, cnt2s;
    __shared__ float partS[8][4][64];           // slot-major: conflict-free b32

    // ---- wave-0 neuron state (quads, R7-proven) ----
    float4 mem1, mem2, b1, b2, spk1, spk2;
    float4 al1, ro1, al2, ro2, oma1, omr1, oma2, omr2, b11r, bsum2;
    if (w == 0) {
        mem1 = *(const float4*)(mem1_0 + bi * H + laneOff);
        mem2 = *(const float4*)(mem2_0 + bi * H + laneOff);
        b1 = make_float4(0.01f, 0.01f, 0.01f, 0.01f);
        b2 = make_float4(0.01f, 0.01f, 0.01f, 0.01f);
        spk1 = make_float4(0.f, 0.f, 0.f, 0.f);
        spk2 = make_float4(0.f, 0.f, 0.f, 0.f);
        float4 tm1 = *(const float4*)(tau_m_h1 + laneOff);
        float4 ta1 = *(const float4*)(tau_adp_h1 + laneOff);
        float4 tm2 = *(const float4*)(tau_m_h2 + laneOff);
        float4 ta2 = *(const float4*)(tau_adp_h2 + laneOff);
        al1.x = expf(-1.f / tm1.x); al1.y = expf(-1.f / tm1.y);
        al1.z = expf(-1.f / tm1.z); al1.w = expf(-1.f / tm1.w);
        ro1.x = expf(-1.f / ta1.x); ro1.y = expf(-1.f / ta1.y);
        ro1.z = expf(-1.f / ta1.z); ro1.w = expf(-1.f / ta1.w);
        al2.x = expf(-1.f / tm2.x); al2.y = expf(-1.f / tm2.y);
        al2.z = expf(-1.f / tm2.z); al2.w = expf(-1.f / tm2.w);
        ro2.x = expf(-1.f / ta2.x); ro2.y = expf(-1.f / ta2.y);
        ro2.z = expf(-1.f / ta2.z); ro2.w = expf(-1.f / ta2.w);
        oma1.x = 1.f - al1.x; oma1.y = 1.f - al1.y; oma1.z = 1.f - al1.z; oma1.w = 1.f - al1.w;
        omr1.x = 1.f - ro1.x; omr1.y = 1.f - ro1.y; omr1.z = 1.f - ro1.z; omr1.w = 1.f - ro1.w;
        oma2.x = 1.f - al2.x; oma2.y = 1.f - al2.y; oma2.z = 1.f - al2.z; oma2.w = 1.f - al2.w;
        omr2.x = 1.f - ro2.x; omr2.y = 1.f - ro2.y; omr2.z = 1.f - ro2.z; omr2.w = 1.f - ro2.w;
        b11r = *(const float4*)(b11v + laneOff);
        float4 b12r = *(const float4*)(b12v + laneOff);
        float4 b22r = *(const float4*)(b22v + laneOff);
        bsum2.x = b12r.x + b22r.x; bsum2.y = b12r.y + b22r.y;
        bsum2.z = b12r.z + b22r.z; bsum2.w = b12r.w + b22r.w;
    }

    // ---- wave-1 output state ----
    float memo = 0.f, alpha_o = 0.f, bo_r = 0.f, accv = 0.f;
    if (w == 1 && lane < D_OUT) {
        memo = memo_0[bi * D_OUT + lane];
        alpha_o = expf(-1.f / tau_m_o[lane]);
        bo_r = bov[lane];
    }

    float4 g11c = make_float4(0.f, 0.f, 0.f, 0.f);
    float4 g22c = make_float4(0.f, 0.f, 0.f, 0.f);

    const float* Up = U + (size_t)bi * T * H + laneOff;
    float4 u_cur;
    if (w == 0) u_cur = *(const float4*)Up;

    for (int t = 0; t < T; ++t) {
        // ---- wave 1: output chain for step t-1 (reads slot-4 partials) ----
        if (w == 1 && t >= 1) {
            float aOc = partS[4][0][lane] + partS[4][1][lane] +
                        partS[4][2][lane] + partS[4][3][lane];
            float o = bo_r + aOc;
            memo = memo * alpha_o + (1.f - alpha_o) * o;
            if (t >= 12) {
                float e = (lane < D_OUT) ? __expf(memo) : 0.f;
                float s = e;
#pragma unroll
                for (int d = 16; d >= 1; d >>= 1) s += __shfl_xor(s, d, 32);
                if (lane < D_OUT) accv += __fdividef(e, s);
            }
        }

        // ---- wave 0: layer-1 update + list 1 ----
        if (w == 0) {
            float4 h1;
            h1.x = u_cur.x + b11r.x + g11c.x; h1.y = u_cur.y + b11r.y + g11c.y;
            h1.z = u_cur.z + b11r.z + g11c.z; h1.w = u_cur.w + b11r.w + g11c.w;
            b1.x = ro1.x * b1.x + omr1.x * spk1.x; b1.y = ro1.y * b1.y + omr1.y * spk1.y;
            b1.z = ro1.z * b1.z + omr1.z * spk1.z; b1.w = ro1.w * b1.w + omr1.w * spk1.w;
            float B1x = 0.01f + 1.8f * b1.x, B1y = 0.01f + 1.8f * b1.y;
            float B1z = 0.01f + 1.8f * b1.z, B1w = 0.01f + 1.8f * b1.w;
            mem1.x = mem1.x * al1.x + oma1.x * h1.x - B1x * spk1.x;
            mem1.y = mem1.y * al1.y + oma1.y * h1.y - B1y * spk1.y;
            mem1.z = mem1.z * al1.z + oma1.z * h1.z - B1z * spk1.z;
            mem1.w = mem1.w * al1.w + oma1.w * h1.w - B1w * spk1.w;
            spk1.x = (mem1.x - B1x > 0.f) ? 1.f : 0.f;
            spk1.y = (mem1.y - B1y > 0.f) ? 1.f : 0.f;
            spk1.z = (mem1.z - B1z > 0.f) ? 1.f : 0.f;
            spk1.w = (mem1.w - B1w > 0.f) ? 1.f : 0.f;
            int n1 = build_list(list1, lane, spk1.x, spk1.y, spk1.z, spk1.w);
            if (lane == 0) cnt1s = (unsigned)n1;
        }
        bar();   // A: list1 + cnt ready

        // u-prefetch in gather-1's shadow
        float4 u_nxt;
        if (w == 0) u_nxt = *(const float4*)(Up + H);
        Up += H;

        int nr16a = (int)((cnt1s + 15u) & ~15u);
        v2f a1[4];
        gatherP(list1, nr16a, w, C1, soff, a1);
#pragma unroll
        for (int q = 0; q < 4; ++q) {
            partS[2 * q][w][lane] = a1[q].x;
            partS[2 * q + 1][w][lane] = a1[q].y;
        }
        bar();   // B: layer-1 partials ready

        if (w == 0) {
            float g[8];
#pragma unroll
            for (int s = 0; s < 8; ++s)
                g[s] = a1[s >> 1][s & 1] + partS[s][1][lane] + partS[s][2][lane] +
                       partS[s][3][lane];
            g11c = make_float4(g[4], g[5], g[6], g[7]);

            float4 h2;
            h2.x = bsum2.x + g22c.x + g[0]; h2.y = bsum2.y + g22c.y + g[1];
            h2.z = bsum2.z + g22c.z + g[2]; h2.w = bsum2.w + g22c.w + g[3];
            b2.x = ro2.x * b2.x + omr2.x * spk2.x; b2.y = ro2.y * b2.y + omr2.y * spk2.y;
            b2.z = ro2.z * b2.z + omr2.z * spk2.z; b2.w = ro2.w * b2.w + omr2.w * spk2.w;
            float B2x = 0.01f + 1.8f * b2.x, B2y = 0.01f + 1.8f * b2.y;
            float B2z = 0.01f + 1.8f * b2.z, B2w = 0.01f + 1.8f * b2.w;
            mem2.x = mem2.x * al2.x + oma2.x * h2.x - B2x * spk2.x;
            mem2.y = mem2.y * al2.y + oma2.y * h2.y - B2y * spk2.y;
            mem2.z = mem2.z * al2.z + oma2.z * h2.z - B2z * spk2.z;
            mem2.w = mem2.w * al2.w + oma2.w * h2.w - B2w * spk2.w;
            spk2.x = (mem2.x - B2x > 0.f) ? 1.f : 0.f;
            spk2.y = (mem2.y - B2y > 0.f) ? 1.f : 0.f;
            spk2.z = (mem2.z - B2z > 0.f) ? 1.f : 0.f;
            spk2.w = (mem2.w - B2w > 0.f) ? 1.f : 0.f;
            int n2 = build_list(list2, lane, spk2.x, spk2.y, spk2.z, spk2.w);
            if (lane == 0) cnt2s = (unsigned)n2;
        }
        bar();   // C: list2 + cnt ready

        int nr16b = (int)((cnt2s + 15u) & ~15u);
        v2f a2[4];
        gatherP(list2, nr16b, w, C2, soff, a2);
#pragma unroll
        for (int q = 0; q < 4; ++q) {
            partS[2 * q][w][lane] = a2[q].x;
            partS[2 * q + 1][w][lane] = a2[q].y;
        }
        bar();   // D: layer-2 partials ready

        if (w == 0) {
            g22c.x = a2[0].x + partS[0][1][lane] + partS[0][2][lane] + partS[0][3][lane];
            g22c.y = a2[0].y + partS[1][1][lane] + partS[1][2][lane] + partS[1][3][lane];
            g22c.z = a2[1].x + partS[2][1][lane] + partS[2][2][lane] + partS[2][3][lane];
            g22c.w = a2[1].y + partS[3][1][lane] + partS[3][2][lane] + partS[3][3][lane];
            u_cur = u_nxt;
        }
    }

    // final flush (memo(T-1) + softmax) on wave 1
    if (w == 1) {
        float aOc = partS[4][0][lane] + partS[4][1][lane] +
                    partS[4][2][lane] + partS[4][3][lane];
        float o = bo_r + aOc;
        memo = memo * alpha_o + (1.f - alpha_o) * o;
        float e = (lane < D_OUT) ? __expf(memo) : 0.f;
        float s = e;
#pragma unroll
        for (int d = 16; d >= 1; d >>= 1) s += __shfl_xor(s, d, 32);
        if (lane < D_OUT) {
            accv += __fdividef(e, s);
            out[bi * D_OUT + lane] = accv;
        }
    }
}

// ---------------------------------------------------------------------------
extern "C" void kernel_launch(void* const* d_in, const int* in_sizes, int n_in,
                              void* d_out, int out_size, void* d_ws, size_t ws_size,
                              hipStream_t stream) {
    const float* x          = (const float*)d_in[0];
    const float* mem1_0     = (const float*)d_in[1];
    const float* mem2_0     = (const float*)d_in[2];
    const float* memo_0     = (const float*)d_in[3];
    const float* Wi1        = (const float*)d_in[4];
    const float* bi1        = (const float*)d_in[5];
    const float* W11        = (const float*)d_in[6];
    const float* b11        = (const float*)d_in[7];
    const float* W12        = (const float*)d_in[8];
    const float* b12        = (const float*)d_in[9];
    const float* W22        = (const float*)d_in[10];
    const float* b22        = (const float*)d_in[11];
    const float* Wo         = (const float*)d_in[12];
    const float* bo         = (const float*)d_in[13];
    const float* tau_adp_h1 = (const float*)d_in[14];
    const float* tau_adp_h2 = (const float*)d_in[15];
    const float* tau_m_h1   = (const float*)d_in[16];
    const float* tau_m_h2   = (const float*)d_in[17];
    const float* tau_m_o    = (const float*)d_in[18];

    float* U = (float*)d_ws;                                       // [32001][256] f32
    unsigned short* C1 = (unsigned short*)(U + ((size_t)BATCH * T + 1) * H); // bf16
    unsigned short* C2 = C1 + N_C;                                 // bf16
    unsigned short* Wi1p = C2 + N_C;                               // bf16

    int prep_total = 2 * N_C + N_WP;
    prep_k<<<(prep_total + 255) / 256, 256, 0, stream>>>(
        Wi1, W11, W12, W22, Wo, Wi1p, C1, C2);

    gemm_u_k<<<(BATCH * T) / 64, 256, 0, stream>>>(x, Wi1p, bi1, U);

    recurrent_k<<<BATCH, 256, 0, stream>>>(U, mem1_0, mem2_0, memo_0,
                                           b11, b12, b22, bo,
                                           tau_adp_h1, tau_adp_h2,
                                           tau_m_h1, tau_m_h2, tau_m_o,
                                           C1, C2, (float*)d_out);
}

// Round 7
// 439.138 us; speedup vs baseline: 1.7316x; 1.7316x over previous
//
#include <hip/hip_runtime.h>
#include <math.h>

#define BATCH 128
#define T 250
#define D_IN 700
#define H 256
#define D_OUT 20

typedef float v2f __attribute__((ext_vector_type(2)));
typedef __attribute__((ext_vector_type(8))) short bf16x8;
typedef __attribute__((ext_vector_type(4))) float f32x4;

static __device__ __forceinline__ unsigned short f2b(float f) {
    unsigned u = __float_as_uint(f);
    u += 0x7FFFu + ((u >> 16) & 1u);
    return (unsigned short)(u >> 16);
}

// Raw barrier: LDS ordering only (lgkmcnt). No vmcnt drain so global loads
// (u prefetch, gather pipeline) stay in flight across it.
static __device__ __forceinline__ void bar() {
    asm volatile("s_waitcnt lgkmcnt(0)" ::: "memory");
    __builtin_amdgcn_s_barrier();
    asm volatile("" ::: "memory");
}

// Padded LDS partial index: 8 cols -> stride 10 (breaks the 16-way stride-32B
// conflict on partial writes; readers use the same mapping).
#define PIDX(c) (10 * ((c) >> 3) + ((c) & 7))

// ---------------------------------------------------------------------------
// Workspace layout:
//   U     [32001][256] f32   (pad row: u-prefetch overrun at t=249, batch 127)
//   C1f   [257][512] f32     row k: col p<256 -> W12T[k][p]; p>=256 -> W11T[k][p-256]
//   C2f   [257][512] f32     row k: col p<256 -> W22T[k][p]; p in [256,276) -> Wo[p-256][k]; else 0
//   Wi1p  [256][704] bf16    cols 700..703 zero (MFMA K-pad)
//   row 256 of C1f/C2f is all-zero (spike-list padding target)
//
// R7: two-track pipelined recurrence. DAG: update1(t) needs only G1(t-1);
// update2(t) needs G1(t)+G2(t-1); output(s) needs G2(s). So track A
// (waves 0,1) runs layer 1 at step t while track B (waves 2,3) runs layer 2
// at step t-1 and the output chain at t-2 — ONE barrier per window instead
// of 4, and no wave executes update+list+gather+reduce serially.
// ---------------------------------------------------------------------------
#define N_C  (257 * 512)
#define N_WP (256 * 704)

__global__ void prep_k(const float* __restrict__ Wi1, const float* __restrict__ W11,
                       const float* __restrict__ W12, const float* __restrict__ W22,
                       const float* __restrict__ Wo,
                       unsigned short* __restrict__ Wi1p, float* __restrict__ C1f,
                       float* __restrict__ C2f) {
    int idx = blockIdx.x * 256 + threadIdx.x;
    if (idx < N_C) {
        int k = idx >> 9, p = idx & 511;
        float v = 0.f;
        if (k < H) v = (p < 256) ? W12[p * H + k] : W11[(p - 256) * H + k];
        C1f[idx] = v;
        return;
    }
    idx -= N_C;
    if (idx < N_C) {
        int k = idx >> 9, p = idx & 511;
        float v = 0.f;
        if (k < H) {
            if (p < 256) v = W22[p * H + k];
            else if (p - 256 < D_OUT) v = Wo[(p - 256) * H + k];
        }
        C2f[idx] = v;
        return;
    }
    idx -= N_C;
    if (idx < N_WP) {
        int h = idx / 704, k = idx - h * 704;
        Wi1p[idx] = (k < D_IN) ? f2b(Wi1[h * D_IN + k]) : (unsigned short)0;
    }
}

// ---------------------------------------------------------------------------
// U = x @ Wi1^T + bi1 via MFMA 16x16x32 bf16 — UNCHANGED (proven).
// ---------------------------------------------------------------------------
__global__ __launch_bounds__(256) void gemm_u_k(const float* __restrict__ x,
                                                const unsigned short* __restrict__ Wi1p,
                                                const float* __restrict__ bi1,
                                                float* __restrict__ U) {
    const int lane = threadIdx.x & 63;
    const int wv = threadIdx.x >> 6;
    const int quad = lane >> 4;
    const int nl = lane & 15;
    const int mbase = blockIdx.x * 64 + wv * 16;
    const int m = mbase + nl;

    f32x4 acc[16];
#pragma unroll
    for (int i = 0; i < 16; ++i) acc[i] = (f32x4)(0.f);

    float bias[16];
#pragma unroll
    for (int nt = 0; nt < 16; ++nt) bias[nt] = bi1[nt * 16 + nl];

    const float* xrow = x + (size_t)m * D_IN;
    const unsigned short* brow = Wi1p + nl * 704 + quad * 8;

    for (int k0 = 0; k0 < 704; k0 += 32) {
        int ka = k0 + quad * 8;
        int ka2 = (ka + 4 <= 696) ? ka + 4 : 696;
        float4 q0 = *(const float4*)(xrow + ka);
        float4 q1 = *(const float4*)(xrow + ka2);
        bf16x8 af;
        af[0] = (short)f2b(q0.x); af[1] = (short)f2b(q0.y);
        af[2] = (short)f2b(q0.z); af[3] = (short)f2b(q0.w);
        af[4] = (short)f2b(q1.x); af[5] = (short)f2b(q1.y);
        af[6] = (short)f2b(q1.z); af[7] = (short)f2b(q1.w);

        const unsigned short* bp = brow + k0;
        bf16x8 bf[16];
#pragma unroll
        for (int nt = 0; nt < 16; ++nt)
            bf[nt] = *(const bf16x8*)(bp + nt * 16 * 704);
#pragma unroll
        for (int nt = 0; nt < 16; ++nt)
            acc[nt] = __builtin_amdgcn_mfma_f32_16x16x32_bf16(af, bf[nt], acc[nt], 0, 0, 0);
    }

#pragma unroll
    for (int nt = 0; nt < 16; ++nt) {
#pragma unroll
        for (int r = 0; r < 4; ++r) {
            U[(size_t)(mbase + quad * 4 + r) * H + nt * 16 + nl] = acc[nt][r] + bias[nt];
        }
    }
}

// ---------------------------------------------------------------------------
// Gather: per wave, its own spike list (own 128 neurons), full 512-col f32
// rows, 8 floats/lane via 2 dwordx4; 2x8-row rotation (R0-proven shape).
// ---------------------------------------------------------------------------
static __device__ __forceinline__ void ld8f(const unsigned* __restrict__ L, int c,
                                            const float* __restrict__ Cb, unsigned l8,
                                            f32x4* ba, f32x4* bb) {
    uint4 ia = *(const uint4*)(L + c);
    uint4 ib = *(const uint4*)(L + c + 4);
    unsigned I[8] = {ia.x, ia.y, ia.z, ia.w, ib.x, ib.y, ib.z, ib.w};
#pragma unroll
    for (int j = 0; j < 8; ++j) {
        const float* p = Cb + ((unsigned)I[j] << 9) + l8;
        ba[j] = *(const f32x4*)p;
        bb[j] = *(const f32x4*)(p + 4);
    }
}

static __device__ __forceinline__ void acc8(const f32x4* ba, const f32x4* bb,
                                            f32x4& A0, f32x4& A1) {
#pragma unroll
    for (int j = 0; j < 8; ++j) { A0 += ba[j]; A1 += bb[j]; }
}

static __device__ __forceinline__ void gather8(const unsigned* __restrict__ L, int n,
                                               const float* __restrict__ Cb, unsigned l8,
                                               f32x4& A0, f32x4& A1) {
    A0 = (f32x4)(0.f);
    A1 = (f32x4)(0.f);
    int nr = (n + 7) & ~7;
    if (nr == 0) return;
    f32x4 xa[8], xb[8], ya[8], yb[8];
    ld8f(L, 0, Cb, l8, xa, xb);
    if (nr == 8) { acc8(xa, xb, A0, A1); return; }
    ld8f(L, 8, Cb, l8, ya, yb);
    int c = 16;
    for (; c + 16 <= nr; c += 16) {
        acc8(xa, xb, A0, A1); ld8f(L, c, Cb, l8, xa, xb);
        acc8(ya, yb, A0, A1); ld8f(L, c + 8, Cb, l8, ya, yb);
    }
    if (nr - c == 8) {
        acc8(xa, xb, A0, A1); ld8f(L, c, Cb, l8, xa, xb);
        acc8(ya, yb, A0, A1); acc8(xa, xb, A0, A1);
    } else {
        acc8(xa, xb, A0, A1); acc8(ya, yb, A0, A1);
    }
}

// ---------------------------------------------------------------------------
// Recurrent: one BLOCK (4 waves) per batch element, two pipelined tracks.
// ---------------------------------------------------------------------------
__global__ __launch_bounds__(256, 1) void recurrent_k(
    const float* __restrict__ U,
    const float* __restrict__ mem1_0, const float* __restrict__ mem2_0,
    const float* __restrict__ memo_0,
    const float* __restrict__ b11v, const float* __restrict__ b12v,
    const float* __restrict__ b22v, const float* __restrict__ bov,
    const float* __restrict__ tau_adp_h1, const float* __restrict__ tau_adp_h2,
    const float* __restrict__ tau_m_h1, const float* __restrict__ tau_m_h2,
    const float* __restrict__ tau_m_o,
    const float* __restrict__ C1f, const float* __restrict__ C2f,
    float* __restrict__ out)
{
    const int tid = threadIdx.x;
    const int lane = tid & 63;
    const int w = tid >> 6;          // wave 0..3
    const int hw = w & 1;            // wave-in-track
    const bool trackA = (w < 2);
    const int bi = blockIdx.x;
    const int th = hw * 64 + lane;   // 0..127 thread-in-track
    const int n0 = 2 * th;           // first owned neuron
    const unsigned woff = hw * 128;  // this wave's spike-row base
    const unsigned l8 = (unsigned)lane * 8;  // float offset of lane's 8 cols

    __shared__ float PA[2][2][640];                 // [wave][buf][PIDX(col)]
    __shared__ float PB[2][3][640];
    __shared__ __align__(16) unsigned lists[4][192];

    // zero partial buffers (only PA[*][1], PB[*][2] strictly needed)
    for (int i = tid; i < 2 * 2 * 640; i += 256) ((float*)PA)[i] = 0.f;
    for (int i = tid; i < 2 * 3 * 640; i += 256) ((float*)PB)[i] = 0.f;
    __syncthreads();

    // ---- track A state: layer-1, 2 neurons per thread ----
    v2f mem1 = (v2f)(0.f), b1v = (v2f)(0.f), spk1 = (v2f)(0.f);
    v2f al1 = (v2f)(0.f), ro1 = (v2f)(0.f), oma1 = (v2f)(0.f), omr1 = (v2f)(0.f);
    v2f b11p = (v2f)(0.f);
    if (trackA) {
        mem1 = *(const v2f*)(mem1_0 + bi * H + n0);
        b1v = (v2f)(0.01f);
        v2f tm = *(const v2f*)(tau_m_h1 + n0);
        v2f ta = *(const v2f*)(tau_adp_h1 + n0);
        al1.x = __expf(-1.f / tm.x); al1.y = __expf(-1.f / tm.y);
        ro1.x = __expf(-1.f / ta.x); ro1.y = __expf(-1.f / ta.y);
        oma1 = 1.f - al1; omr1 = 1.f - ro1;
        b11p = *(const v2f*)(b11v + n0);
    }

    // ---- track B state: layer-2, 2 neurons per thread ----
    v2f mem2 = (v2f)(0.f), b2v = (v2f)(0.f), spk2 = (v2f)(0.f);
    v2f al2 = (v2f)(0.f), ro2 = (v2f)(0.f), oma2 = (v2f)(0.f), omr2 = (v2f)(0.f);
    v2f bs2 = (v2f)(0.f);
    if (!trackA) {
        mem2 = *(const v2f*)(mem2_0 + bi * H + n0);
        b2v = (v2f)(0.01f);
        v2f tm = *(const v2f*)(tau_m_h2 + n0);
        v2f ta = *(const v2f*)(tau_adp_h2 + n0);
        al2.x = __expf(-1.f / tm.x); al2.y = __expf(-1.f / tm.y);
        ro2.x = __expf(-1.f / ta.x); ro2.y = __expf(-1.f / ta.y);
        oma2 = 1.f - al2; omr2 = 1.f - ro2;
        bs2 = *(const v2f*)(b12v + n0) + *(const v2f*)(b22v + n0);
    }

    // ---- wave-2 output state: 2 outputs per lane, lanes 0..9 ----
    v2f memo = (v2f)(0.f), alo = (v2f)(0.f), omo = (v2f)(0.f);
    v2f bop = (v2f)(0.f), acco = (v2f)(0.f);
    const bool outlane = (w == 2 && lane < 10);
    if (outlane) {
        memo = *(const v2f*)(memo_0 + bi * D_OUT + 2 * lane);
        v2f tm = *(const v2f*)(tau_m_o + 2 * lane);
        alo.x = __expf(-1.f / tm.x); alo.y = __expf(-1.f / tm.y);
        omo = 1.f - alo;
        bop = *(const v2f*)(bov + 2 * lane);
    }

    const float* Up = U + (size_t)bi * T * H + n0;
    v2f u_cur = (v2f)(0.f), u_nxt = (v2f)(0.f);
    if (trackA) u_cur = *(const v2f*)Up;
    const unsigned long long below = (1ull << lane) - 1ull;

    for (int t = 0; t < 252; ++t) {
        const int rbA = (t + 1) & 1;     // (t-1) & 1
        const int wbA = t & 1;
        const int rsB = (t + 1) % 3;     // (t-2) mod 3
        const int wsB = (t + 2) % 3;     // (t-1) mod 3

        if (trackA && t < 250) {
            // g11(t-1) = sum of both track-A wave partials
            v2f g11 = *(const v2f*)&PA[0][rbA][PIDX(256 + n0)] +
                      *(const v2f*)&PA[1][rbA][PIDX(256 + n0)];
            v2f h1 = u_cur + b11p + g11;
            b1v = ro1 * b1v + omr1 * spk1;
            v2f B1 = 0.01f + 1.8f * b1v;
            mem1 = mem1 * al1 + oma1 * h1 - B1 * spk1;
            v2f d = mem1 - B1;
            spk1.x = (d.x > 0.f) ? 1.f : 0.f;
            spk1.y = (d.y > 0.f) ? 1.f : 0.f;

            // wave-private spike list (rows of this wave's 128 neurons)
            unsigned long long m0 = __ballot(spk1.x != 0.f);
            unsigned long long m1 = __ballot(spk1.y != 0.f);
            int c0 = __popcll(m0);
            int n = c0 + __popcll(m1);
            unsigned* L = lists[w];
            if (spk1.x != 0.f) L[__popcll(m0 & below)] = woff + 2 * lane;
            if (spk1.y != 0.f) L[c0 + __popcll(m1 & below)] = woff + 2 * lane + 1;
            L[n + lane] = 256u;          // pads -> all-zero row
            asm volatile("s_waitcnt lgkmcnt(0)" ::: "memory");
            __builtin_amdgcn_wave_barrier();

            if (t + 1 < 250) u_nxt = *(const v2f*)(Up + H);
            Up += H;

            f32x4 A0, A1;
            gather8(L, n, C1f, l8, A0, A1);

            float* pw = &PA[hw][wbA][10 * lane];
            const v2f* ap = (const v2f*)&A0;
            const v2f* bp = (const v2f*)&A1;
            *(v2f*)(pw + 0) = ap[0];
            *(v2f*)(pw + 2) = ap[1];
            *(v2f*)(pw + 4) = bp[0];
            *(v2f*)(pw + 6) = bp[1];

            u_cur = u_nxt;
        }

        if (w == 2 && t >= 2) {
            // output chain for step s = t-2 (reads G2(s) from slot rsB)
            v2f e = (v2f)(0.f);
            if (lane < 10) {
                v2f aO = *(const v2f*)&PB[0][rsB][PIDX(256 + 2 * lane)] +
                         *(const v2f*)&PB[1][rsB][PIDX(256 + 2 * lane)];
                memo = memo * alo + omo * (bop + aO);
                e.x = __expf(memo.x);
                e.y = __expf(memo.y);
            }
            if (t >= 13) {
                float s = e.x + e.y;
#pragma unroll
                for (int dd = 8; dd >= 1; dd >>= 1) s += __shfl_xor(s, dd, 16);
                if (lane < 10) acco += e * __fdividef(1.f, s);
            }
        }

        if (!trackA && t >= 1 && t < 251) {
            // update2(t-1): g12 from G1(t-1), g22 from G2(t-2)
            v2f g12 = *(const v2f*)&PA[0][rbA][PIDX(n0)] +
                      *(const v2f*)&PA[1][rbA][PIDX(n0)];
            v2f g22 = *(const v2f*)&PB[0][rsB][PIDX(n0)] +
                      *(const v2f*)&PB[1][rsB][PIDX(n0)];
            v2f h2 = bs2 + g22 + g12;
            b2v = ro2 * b2v + omr2 * spk2;
            v2f B2 = 0.01f + 1.8f * b2v;
            mem2 = mem2 * al2 + oma2 * h2 - B2 * spk2;
            v2f d = mem2 - B2;
            spk2.x = (d.x > 0.f) ? 1.f : 0.f;
            spk2.y = (d.y > 0.f) ? 1.f : 0.f;

            unsigned long long m0 = __ballot(spk2.x != 0.f);
            unsigned long long m1 = __ballot(spk2.y != 0.f);
            int c0 = __popcll(m0);
            int n = c0 + __popcll(m1);
            unsigned* L = lists[w];
            if (spk2.x != 0.f) L[__popcll(m0 & below)] = woff + 2 * lane;
            if (spk2.y != 0.f) L[c0 + __popcll(m1 & below)] = woff + 2 * lane + 1;
            L[n + lane] = 256u;
            asm volatile("s_waitcnt lgkmcnt(0)" ::: "memory");
            __builtin_amdgcn_wave_barrier();

            f32x4 A0, A1;
            gather8(L, n, C2f, l8, A0, A1);

            float* pw = &PB[hw][wsB][10 * lane];
            const v2f* ap = (const v2f*)&A0;
            const v2f* bp = (const v2f*)&A1;
            *(v2f*)(pw + 0) = ap[0];
            *(v2f*)(pw + 2) = ap[1];
            *(v2f*)(pw + 4) = bp[0];
            *(v2f*)(pw + 6) = bp[1];
        }

        bar();   // single barrier per window
    }

    if (outlane) {
        *(v2f*)(out + bi * D_OUT + 2 * lane) = acco;
    }
}

// ---------------------------------------------------------------------------
extern "C" void kernel_launch(void* const* d_in, const int* in_sizes, int n_in,
                              void* d_out, int out_size, void* d_ws, size_t ws_size,
                              hipStream_t stream) {
    const float* x          = (const float*)d_in[0];
    const float* mem1_0     = (const float*)d_in[1];
    const float* mem2_0     = (const float*)d_in[2];
    const float* memo_0     = (const float*)d_in[3];
    const float* Wi1        = (const float*)d_in[4];
    const float* bi1        = (const float*)d_in[5];
    const float* W11        = (const float*)d_in[6];
    const float* b11        = (const float*)d_in[7];
    const float* W12        = (const float*)d_in[8];
    const float* b12        = (const float*)d_in[9];
    const float* W22        = (const float*)d_in[10];
    const float* b22        = (const float*)d_in[11];
    const float* Wo         = (const float*)d_in[12];
    const float* bo         = (const float*)d_in[13];
    const float* tau_adp_h1 = (const float*)d_in[14];
    const float* tau_adp_h2 = (const float*)d_in[15];
    const float* tau_m_h1   = (const float*)d_in[16];
    const float* tau_m_h2   = (const float*)d_in[17];
    const float* tau_m_o    = (const float*)d_in[18];

    float* U = (float*)d_ws;                            // [32001][256] f32
    float* C1f = U + ((size_t)BATCH * T + 1) * H;       // [257][512] f32
    float* C2f = C1f + N_C;                             // [257][512] f32
    unsigned short* Wi1p = (unsigned short*)(C2f + N_C);// [256][704] bf16

    int prep_total = 2 * N_C + N_WP;
    prep_k<<<(prep_total + 255) / 256, 256, 0, stream>>>(
        Wi1, W11, W12, W22, Wo, Wi1p, C1f, C2f);

    gemm_u_k<<<(BATCH * T) / 64, 256, 0, stream>>>(x, Wi1p, bi1, U);

    recurrent_k<<<BATCH, 256, 0, stream>>>(U, mem1_0, mem2_0, memo_0,
                                           b11, b12, b22, bo,
                                           tau_adp_h1, tau_adp_h2,
                                           tau_m_h1, tau_m_h2, tau_m_o,
                                           C1f, C2f, (float*)d_out);
}

// Round 8
// 384.487 us; speedup vs baseline: 1.9777x; 1.1421x over previous
//
#include <hip/hip_runtime.h>
#include <math.h>

#define BATCH 128
#define T 250
#define D_IN 700
#define H 256
#define D_OUT 20

typedef float v2f __attribute__((ext_vector_type(2)));
typedef __attribute__((ext_vector_type(8))) short bf16x8;
typedef __attribute__((ext_vector_type(4))) float f32x4;
typedef __attribute__((ext_vector_type(4))) unsigned u32x4;

static __device__ __forceinline__ unsigned short f2b(float f) {
    unsigned u = __float_as_uint(f);
    u += 0x7FFFu + ((u >> 16) & 1u);
    return (unsigned short)(u >> 16);
}

// Raw barrier: LDS ordering only (lgkmcnt). No vmcnt drain so global loads
// (u prefetch, gather pipeline) stay in flight across it.
static __device__ __forceinline__ void bar() {
    asm volatile("s_waitcnt lgkmcnt(0)" ::: "memory");
    __builtin_amdgcn_s_barrier();
    asm volatile("" ::: "memory");
}

// Padded LDS partial index: 8 cols -> stride 10 (2-way max on b64 writes).
#define PIDX(c) (10 * ((c) >> 3) + ((c) & 7))

// ---------------------------------------------------------------------------
// Workspace layout:
//   U     [32001][256] f32   (pad row: u-prefetch overrun at t=249, batch 127)
//   C1b   [257][512] bf16    row k: col p<256 -> W12T[k][p]; p>=256 -> W11T[k][p-256]
//   C2b   [257][512] bf16    row k: col p<256 -> W22T[k][p]; p in [256,276) -> Wo[p-256][k]; else 0
//   Wi1p  [256][704] bf16    cols 700..703 zero (MFMA K-pad)
//   row 256 of C1b/C2b is all-zero (spike-list padding target)
//
// R8: R7's two-track pipeline (proven 1.95x) + the gather was measured at the
// L2 BW ceiling (415KB/window/block -> 37 TB/s aggregate). bf16 rows halve
// L2 bytes (1KB/row, ONE dwordx4/row/lane); 8 waves (1 neuron/lane, 4 waves
// per track) keep the unpack VALU per wave under the halved BW floor and
// reduce the list build to a single ballot. Skew/buffering copied verbatim.
// ---------------------------------------------------------------------------
#define N_C  (257 * 512)
#define N_WP (256 * 704)

__global__ void prep_k(const float* __restrict__ Wi1, const float* __restrict__ W11,
                       const float* __restrict__ W12, const float* __restrict__ W22,
                       const float* __restrict__ Wo,
                       unsigned short* __restrict__ Wi1p, unsigned short* __restrict__ C1,
                       unsigned short* __restrict__ C2) {
    int idx = blockIdx.x * 256 + threadIdx.x;
    if (idx < N_C) {
        int k = idx >> 9, p = idx & 511;
        float v = 0.f;
        if (k < H) v = (p < 256) ? W12[p * H + k] : W11[(p - 256) * H + k];
        C1[idx] = f2b(v);
        return;
    }
    idx -= N_C;
    if (idx < N_C) {
        int k = idx >> 9, p = idx & 511;
        float v = 0.f;
        if (k < H) {
            if (p < 256) v = W22[p * H + k];
            else if (p - 256 < D_OUT) v = Wo[(p - 256) * H + k];
        }
        C2[idx] = f2b(v);
        return;
    }
    idx -= N_C;
    if (idx < N_WP) {
        int h = idx / 704, k = idx - h * 704;
        Wi1p[idx] = (k < D_IN) ? f2b(Wi1[h * D_IN + k]) : (unsigned short)0;
    }
}

// ---------------------------------------------------------------------------
// U = x @ Wi1^T + bi1 via MFMA 16x16x32 bf16 — UNCHANGED (proven).
// ---------------------------------------------------------------------------
__global__ __launch_bounds__(256) void gemm_u_k(const float* __restrict__ x,
                                                const unsigned short* __restrict__ Wi1p,
                                                const float* __restrict__ bi1,
                                                float* __restrict__ U) {
    const int lane = threadIdx.x & 63;
    const int wv = threadIdx.x >> 6;
    const int quad = lane >> 4;
    const int nl = lane & 15;
    const int mbase = blockIdx.x * 64 + wv * 16;
    const int m = mbase + nl;

    f32x4 acc[16];
#pragma unroll
    for (int i = 0; i < 16; ++i) acc[i] = (f32x4)(0.f);

    float bias[16];
#pragma unroll
    for (int nt = 0; nt < 16; ++nt) bias[nt] = bi1[nt * 16 + nl];

    const float* xrow = x + (size_t)m * D_IN;
    const unsigned short* brow = Wi1p + nl * 704 + quad * 8;

    for (int k0 = 0; k0 < 704; k0 += 32) {
        int ka = k0 + quad * 8;
        int ka2 = (ka + 4 <= 696) ? ka + 4 : 696;
        float4 q0 = *(const float4*)(xrow + ka);
        float4 q1 = *(const float4*)(xrow + ka2);
        bf16x8 af;
        af[0] = (short)f2b(q0.x); af[1] = (short)f2b(q0.y);
        af[2] = (short)f2b(q0.z); af[3] = (short)f2b(q0.w);
        af[4] = (short)f2b(q1.x); af[5] = (short)f2b(q1.y);
        af[6] = (short)f2b(q1.z); af[7] = (short)f2b(q1.w);

        const unsigned short* bp = brow + k0;
        bf16x8 bf[16];
#pragma unroll
        for (int nt = 0; nt < 16; ++nt)
            bf[nt] = *(const bf16x8*)(bp + nt * 16 * 704);
#pragma unroll
        for (int nt = 0; nt < 16; ++nt)
            acc[nt] = __builtin_amdgcn_mfma_f32_16x16x32_bf16(af, bf[nt], acc[nt], 0, 0, 0);
    }

#pragma unroll
    for (int nt = 0; nt < 16; ++nt) {
#pragma unroll
        for (int r = 0; r < 4; ++r) {
            U[(size_t)(mbase + quad * 4 + r) * H + nt * 16 + nl] = acc[nt][r] + bias[nt];
        }
    }
}

// ---------------------------------------------------------------------------
// bf16 gather: wave's own list (<=64 rows + pads to mult of 8 -> zero row
// 256). One dwordx4 per row per lane (lane's 8 cols); 2x8-row rotation.
// Unpack: dword -> {lo<<16, hi&mask} as f32, packed v2f accumulate.
// ---------------------------------------------------------------------------
static __device__ __forceinline__ void ld8b(const unsigned* __restrict__ L, int c,
                                            const unsigned short* __restrict__ Cb,
                                            unsigned l8, u32x4* b) {
    uint4 ia = *(const uint4*)(L + c);
    uint4 ib = *(const uint4*)(L + c + 4);
    unsigned I[8] = {ia.x, ia.y, ia.z, ia.w, ib.x, ib.y, ib.z, ib.w};
#pragma unroll
    for (int jj = 0; jj < 8; ++jj)
        b[jj] = *(const u32x4*)(Cb + ((unsigned)I[jj] << 9) + l8);
}

static __device__ __forceinline__ void acc8b(const u32x4* b, v2f* a) {
#pragma unroll
    for (int jj = 0; jj < 8; ++jj) {
#pragma unroll
        for (int q = 0; q < 4; ++q) {
            unsigned u = b[jj][q];
            v2f t;
            t.x = __uint_as_float(u << 16);
            t.y = __uint_as_float(u & 0xffff0000u);
            a[q] += t;
        }
    }
}

static __device__ __forceinline__ void gatherB(const unsigned* __restrict__ L, int n,
                                               const unsigned short* __restrict__ Cb,
                                               unsigned l8, v2f* a) {
    a[0] = (v2f)(0.f); a[1] = (v2f)(0.f); a[2] = (v2f)(0.f); a[3] = (v2f)(0.f);
    int nr = (n + 7) & ~7;
    if (nr == 0) return;
    u32x4 x[8], y[8];
    ld8b(L, 0, Cb, l8, x);
    if (nr == 8) { acc8b(x, a); return; }
    ld8b(L, 8, Cb, l8, y);
    int c = 16;
    for (; c + 16 <= nr; c += 16) {
        acc8b(x, a); ld8b(L, c, Cb, l8, x);
        acc8b(y, a); ld8b(L, c + 8, Cb, l8, y);
    }
    if (nr - c == 8) {
        acc8b(x, a); ld8b(L, c, Cb, l8, x);
        acc8b(y, a); acc8b(x, a);
    } else {
        acc8b(x, a); acc8b(y, a);
    }
}

// ---------------------------------------------------------------------------
// Recurrent: one BLOCK (8 waves, 512 threads) per batch element.
// Waves 0-3 = track A (layer 1, step t), waves 4-7 = track B (layer 2, step
// t-1; wave 4 also runs the output chain at step t-2). 1 neuron per lane.
// One barrier per window.
// ---------------------------------------------------------------------------
__global__ __launch_bounds__(512, 1) void recurrent_k(
    const float* __restrict__ U,
    const float* __restrict__ mem1_0, const float* __restrict__ mem2_0,
    const float* __restrict__ memo_0,
    const float* __restrict__ b11v, const float* __restrict__ b12v,
    const float* __restrict__ b22v, const float* __restrict__ bov,
    const float* __restrict__ tau_adp_h1, const float* __restrict__ tau_adp_h2,
    const float* __restrict__ tau_m_h1, const float* __restrict__ tau_m_h2,
    const float* __restrict__ tau_m_o,
    const unsigned short* __restrict__ C1b, const unsigned short* __restrict__ C2b,
    float* __restrict__ out)
{
    const int tid = threadIdx.x;
    const int lane = tid & 63;
    const int w = tid >> 6;           // 0..7
    const bool trackA = (w < 4);
    const int wt = w & 3;             // wave-in-track
    const int bi = blockIdx.x;
    const int j = wt * 64 + lane;     // owned neuron (both layers)
    const unsigned l8 = (unsigned)lane * 8;   // ushort offset of lane's 8 cols

    __shared__ float PA[4][2][640];
    __shared__ float PB[4][3][640];
    __shared__ __align__(16) unsigned lists[8][128];

    for (int i = tid; i < 4 * 2 * 640; i += 512) ((float*)PA)[i] = 0.f;
    for (int i = tid; i < 4 * 3 * 640; i += 512) ((float*)PB)[i] = 0.f;
    __syncthreads();

    // ---- track A state (layer 1, scalar per lane) ----
    float mem1 = 0.f, b1 = 0.01f, spk1 = 0.f;
    float al1 = 0.f, ro1 = 0.f, oma1 = 0.f, omr1 = 0.f, b11p = 0.f;
    if (trackA) {
        mem1 = mem1_0[bi * H + j];
        al1 = __expf(-1.f / tau_m_h1[j]);
        ro1 = __expf(-1.f / tau_adp_h1[j]);
        oma1 = 1.f - al1; omr1 = 1.f - ro1;
        b11p = b11v[j];
    }

    // ---- track B state (layer 2) ----
    float mem2 = 0.f, b2 = 0.01f, spk2 = 0.f;
    float al2 = 0.f, ro2 = 0.f, oma2 = 0.f, omr2 = 0.f, bs2 = 0.f;
    if (!trackA) {
        mem2 = mem2_0[bi * H + j];
        al2 = __expf(-1.f / tau_m_h2[j]);
        ro2 = __expf(-1.f / tau_adp_h2[j]);
        oma2 = 1.f - al2; omr2 = 1.f - ro2;
        bs2 = b12v[j] + b22v[j];
    }

    // ---- wave-4 output state (1 output/lane, lanes 0..19) ----
    float memo = 0.f, alo = 0.f, omo = 0.f, bop = 0.f, acco = 0.f;
    const bool outl = (w == 4 && lane < D_OUT);
    if (outl) {
        memo = memo_0[bi * D_OUT + lane];
        alo = __expf(-1.f / tau_m_o[lane]);
        omo = 1.f - alo;
        bop = bov[lane];
    }

    const float* Up = U + (size_t)bi * T * H + j;
    float u_cur = trackA ? *Up : 0.f;
    float u_nxt = 0.f;
    const unsigned long long below = (1ull << lane) - 1ull;

    const int pidx_self = 320 + PIDX(j);   // PIDX(256 + j)
    const int pidx_j = PIDX(j);
    const int pidx_out = 320 + PIDX(lane); // PIDX(256 + lane), lanes < 20

    for (int t = 0; t < 252; ++t) {
        const int rbA = (t + 1) & 1;     // (t-1) & 1
        const int wbA = t & 1;
        const int rsB = (t + 1) % 3;     // (t-2) mod 3
        const int wsB = (t + 2) % 3;     // (t-1) mod 3

        if (trackA && t < 250) {
            float g11 = PA[0][rbA][pidx_self] + PA[1][rbA][pidx_self] +
                        PA[2][rbA][pidx_self] + PA[3][rbA][pidx_self];
            float h1 = u_cur + b11p + g11;
            b1 = ro1 * b1 + omr1 * spk1;
            float B1 = 0.01f + 1.8f * b1;
            mem1 = mem1 * al1 + oma1 * h1 - B1 * spk1;
            spk1 = (mem1 - B1 > 0.f) ? 1.f : 0.f;

            unsigned long long m = __ballot(spk1 != 0.f);
            int n = __popcll(m);
            unsigned* L = lists[w];
            if (spk1 != 0.f) L[__popcll(m & below)] = (unsigned)j;
            L[n + lane] = 256u;          // pads -> all-zero row
            asm volatile("s_waitcnt lgkmcnt(0)" ::: "memory");
            __builtin_amdgcn_wave_barrier();

            u_nxt = Up[H];               // pad row covers t=249 overrun
            Up += H;

            v2f a[4];
            gatherB(L, n, C1b, l8, a);

            float* pw = &PA[wt][wbA][10 * lane];
            *(v2f*)(pw + 0) = a[0];
            *(v2f*)(pw + 2) = a[1];
            *(v2f*)(pw + 4) = a[2];
            *(v2f*)(pw + 6) = a[3];
            u_cur = u_nxt;
        }

        if (w == 4 && t >= 2) {
            // output chain for step s = t-2
            float e = 0.f;
            if (lane < D_OUT) {
                float aO = PB[0][rsB][pidx_out] + PB[1][rsB][pidx_out] +
                           PB[2][rsB][pidx_out] + PB[3][rsB][pidx_out];
                memo = memo * alo + omo * (bop + aO);
                e = __expf(memo);
            }
            if (t >= 13) {
                float s = e;
#pragma unroll
                for (int dd = 16; dd >= 1; dd >>= 1) s += __shfl_xor(s, dd, 32);
                if (lane < D_OUT) acco += __fdividef(e, s);
            }
        }

        if (!trackA && t >= 1 && t < 251) {
            // update2(t-1): g12 from G1(t-1), g22 from G2(t-2)
            float g12 = PA[0][rbA][pidx_j] + PA[1][rbA][pidx_j] +
                        PA[2][rbA][pidx_j] + PA[3][rbA][pidx_j];
            float g22 = PB[0][rsB][pidx_j] + PB[1][rsB][pidx_j] +
                        PB[2][rsB][pidx_j] + PB[3][rsB][pidx_j];
            float h2 = bs2 + g22 + g12;
            b2 = ro2 * b2 + omr2 * spk2;
            float B2 = 0.01f + 1.8f * b2;
            mem2 = mem2 * al2 + oma2 * h2 - B2 * spk2;
            spk2 = (mem2 - B2 > 0.f) ? 1.f : 0.f;

            unsigned long long m = __ballot(spk2 != 0.f);
            int n = __popcll(m);
            unsigned* L = lists[w];
            if (spk2 != 0.f) L[__popcll(m & below)] = (unsigned)j;
            L[n + lane] = 256u;
            asm volatile("s_waitcnt lgkmcnt(0)" ::: "memory");
            __builtin_amdgcn_wave_barrier();

            v2f a[4];
            gatherB(L, n, C2b, l8, a);

            float* pw = &PB[wt][wsB][10 * lane];
            *(v2f*)(pw + 0) = a[0];
            *(v2f*)(pw + 2) = a[1];
            *(v2f*)(pw + 4) = a[2];
            *(v2f*)(pw + 6) = a[3];
        }

        bar();   // single barrier per window
    }

    if (outl) out[bi * D_OUT + lane] = acco;
}

// ---------------------------------------------------------------------------
extern "C" void kernel_launch(void* const* d_in, const int* in_sizes, int n_in,
                              void* d_out, int out_size, void* d_ws, size_t ws_size,
                              hipStream_t stream) {
    const float* x          = (const float*)d_in[0];
    const float* mem1_0     = (const float*)d_in[1];
    const float* mem2_0     = (const float*)d_in[2];
    const float* memo_0     = (const float*)d_in[3];
    const float* Wi1        = (const float*)d_in[4];
    const float* bi1        = (const float*)d_in[5];
    const float* W11        = (const float*)d_in[6];
    const float* b11        = (const float*)d_in[7];
    const float* W12        = (const float*)d_in[8];
    const float* b12        = (const float*)d_in[9];
    const float* W22        = (const float*)d_in[10];
    const float* b22        = (const float*)d_in[11];
    const float* Wo         = (const float*)d_in[12];
    const float* bo         = (const float*)d_in[13];
    const float* tau_adp_h1 = (const float*)d_in[14];
    const float* tau_adp_h2 = (const float*)d_in[15];
    const float* tau_m_h1   = (const float*)d_in[16];
    const float* tau_m_h2   = (const float*)d_in[17];
    const float* tau_m_o    = (const float*)d_in[18];

    float* U = (float*)d_ws;                                       // [32001][256] f32
    unsigned short* C1b = (unsigned short*)(U + ((size_t)BATCH * T + 1) * H);
    unsigned short* C2b = C1b + N_C;
    unsigned short* Wi1p = C2b + N_C;

    int prep_total = 2 * N_C + N_WP;
    prep_k<<<(prep_total + 255) / 256, 256, 0, stream>>>(
        Wi1, W11, W12, W22, Wo, Wi1p, C1b, C2b);

    gemm_u_k<<<(BATCH * T) / 64, 256, 0, stream>>>(x, Wi1p, bi1, U);

    recurrent_k<<<BATCH, 512, 0, stream>>>(U, mem1_0, mem2_0, memo_0,
                                           b11, b12, b22, bo,
                                           tau_adp_h1, tau_adp_h2,
                                           tau_m_h1, tau_m_h2, tau_m_o,
                                           C1b, C2b, (float*)d_out);
}